// Round 12
// baseline (163.042 us; speedup 1.0000x reference)
//
#include <hip/hip_runtime.h>
#include <hip/hip_bf16.h>

// GCN forward, algebraically collapsed (no nonlinearity between convs, mean pool):
//   g = (1/n)*((A^T u)^T X)@W1@W2 + (1/n)*(sum u)*(b1@W2) + b2,  A = D^-1/2(Adj+I)D^-1/2
// Round 12: fused kernel, relaxed-atomic (sc1) cross-phase buffers + epoch-flag
// barriers (round 11: ~4us/barrier vs 25 for rel/acq). New: int4/float4 edge
// batches (gathers grouped before LDS atomics), 4 ranges x 64 slices (replicas
// 128->64: fold loads halve, partials 10->5 MB/pass), XCD-aligned slice mapping
// (4 same-slice blocks share an XCD L2 -> edges hit HBM once per pass).

#define D_IN 128
#define D_HID 256
#define D_DENSE 128
#define NRANGE 4
#define RB 5120           // bins per range (20 KB LDS); range 3 holds 4640
#define NS 64             // edge slices; PER = 10000 edges each (64*10000 = E)
#define PER 10000
#define NTILE 157         // ceil(20000/128) fold/tail tiles (128 | 5120)

__device__ __forceinline__ float ld_ag(const float* p) {
    return __hip_atomic_load(p, __ATOMIC_RELAXED, __HIP_MEMORY_SCOPE_AGENT);
}
__device__ __forceinline__ void st_ag(float* p, float v) {
    __hip_atomic_store(p, v, __ATOMIC_RELAXED, __HIP_MEMORY_SCOPE_AGENT);
}
// epoch-flag barrier: no init needed (0xAA poison as int is negative < phase)
__device__ __forceinline__ void ph_arrive(int* flags, int phase) {
    __syncthreads();   // drains vmcnt before s_barrier -> stores visible
    if (threadIdx.x == 0)
        __hip_atomic_store(&flags[blockIdx.x], phase,
                           __ATOMIC_RELAXED, __HIP_MEMORY_SCOPE_AGENT);
}
__device__ __forceinline__ void ph_wait(int* flags, int phase) {
    if (threadIdx.x < 256) {
        while (__hip_atomic_load(&flags[threadIdx.x],
                                 __ATOMIC_RELAXED, __HIP_MEMORY_SCOPE_AGENT) < phase)
            __builtin_amdgcn_s_sleep(2);
    }
    __syncthreads();
}

struct Params {
    const float* x; const int* row; const int* col; const float* w;
    const float* W1; const float* b1; const float* W2; const float* b2;
    const float* Wd1; const float* bd1; const float* Wd2; const float* bd2;
    float* out;
    float* part; float* dinv; float* u; float* s_part; float* S_u_part;
    float* M; float* c2; int* flags;
    int N; int E; float inv_n;
};

__global__ __launch_bounds__(1024) void k_all(Params p) {
    __shared__ float lds[RB];                     // 20 KB, reused per phase
    const int b = blockIdx.x, tid = threadIdx.x;
    const int N = p.N, E = p.E;

    // ---- edge scatter: block (range g, slice s); int4 batches of 4 edges ---
    auto scatter = [&](const int* tgt, const int* src, int mode) {
        const int g = b >> 6, s = b & 63;         // b = g*64 + s (b%8 == s%8: XCD share)
        const int base = g * RB;
        const int lim  = min(RB, N - base);
        const int e0 = s * PER, e1 = min(e0 + PER, E);
        float* outp = p.part + (size_t)b * RB;    // replica (g,s)
        for (int i = tid; i < lim; i += 1024) lds[i] = 0.f;
        __syncthreads();
        for (int e = e0 + tid * 4; e + 3 < e1; e += 4096) {
            int4  t4 = *(const int4*)(tgt + e);
            float4 w4 = *(const float4*)(p.w + e);
            float v0 = w4.x, v1 = w4.y, v2 = w4.z, v3 = w4.w;
            if (mode != 0) {
                int4 s4 = *(const int4*)(src + e);
                float d0 = p.dinv[s4.x], d1 = p.dinv[s4.y];
                float d2 = p.dinv[s4.z], d3 = p.dinv[s4.w];
                if (mode == 2) {
                    d0 *= p.u[s4.x]; d1 *= p.u[s4.y];
                    d2 *= p.u[s4.z]; d3 *= p.u[s4.w];
                }
                v0 *= d0; v1 *= d1; v2 *= d2; v3 *= d3;
            }
            int t0 = t4.x - base, t1 = t4.y - base;
            int t2 = t4.z - base, t3 = t4.w - base;
            if ((unsigned)t0 < (unsigned)lim) atomicAdd(&lds[t0], v0);
            if ((unsigned)t1 < (unsigned)lim) atomicAdd(&lds[t1], v1);
            if ((unsigned)t2 < (unsigned)lim) atomicAdd(&lds[t2], v2);
            if ((unsigned)t3 < (unsigned)lim) atomicAdd(&lds[t3], v3);
        }
        __syncthreads();
        for (int i = tid; i < lim; i += 1024) st_ag(outp + i, lds[i]);
    };

    // ---- fold 64 replicas + node math (blocks 0..NTILE-1) ------------------
    auto fold = [&](int mode) {
        const int j = tid & 127, rg = tid >> 7;   // rg in [0,8): 8 replicas each
        const int i = b * 128 + j;
        const bool act = i < N;
        const int g = b / 40;                     // tile-uniform (128 | 5120)
        const int jj = i - g * RB;
        float sv = 0.f;
        if (act) {
            const float* pp = p.part + (size_t)(g * 64 + rg * 8) * RB + jj;
            #pragma unroll
            for (int r = 0; r < 8; ++r) sv += ld_ag(pp + (size_t)r * RB);
        }
        lds[rg * 128 + j] = sv;
        __syncthreads();
        float ui = 0.f;
        if (rg == 0) {
            float tot = 0.f;
            #pragma unroll
            for (int q = 0; q < 8; ++q) tot += lds[q * 128 + j];
            if (act) {
                if (mode == 0) st_ag(p.dinv + i, rsqrtf(tot + 1.0f));  // +1 self-loop
                else { float d = p.dinv[i]; ui = d * (tot + d); st_ag(p.u + i, ui); }
            }
        }
        if (mode == 1) {                          // per-block S_u partial
            float v = ui;                         // nonzero only waves 0-1
            #pragma unroll
            for (int off = 32; off > 0; off >>= 1) v += __shfl_down(v, off, 64);
            if (tid < 128 && (tid & 63) == 0) lds[1028 + (tid >> 6)] = v;
            __syncthreads();
            if (tid == 0) st_ag(p.S_u_part + b, lds[1028] + lds[1029]);
        }
    };

    // ---- M = W1@W2, c2 = b1@W2 (blocks NTILE..NTILE+63 during F0) ----------
    auto precompute = [&]() {
        int q = b - NTILE;                        // 0..63: 4 cols of M each
        lds[tid] = p.W2[(tid >> 2) * 256 + q * 4 + (tid & 3)];
        __syncthreads();
        int wvi = tid >> 6, lane = tid & 63;
        for (int kr = 0; kr < 8; ++kr) {
            int k = wvi * 8 + kr;                 // 16 waves x 8 = 128 rows
            float a0 = 0, a1 = 0, a2 = 0, a3 = 0;
            #pragma unroll
            for (int it = 0; it < 4; ++it) {
                int j = it * 64 + lane;
                float a = p.W1[k * 256 + j];
                a0 += a * lds[j*4+0]; a1 += a * lds[j*4+1];
                a2 += a * lds[j*4+2]; a3 += a * lds[j*4+3];
            }
            #pragma unroll
            for (int off = 32; off > 0; off >>= 1) {
                a0 += __shfl_down(a0, off, 64); a1 += __shfl_down(a1, off, 64);
                a2 += __shfl_down(a2, off, 64); a3 += __shfl_down(a3, off, 64);
            }
            if (lane == 0) {
                st_ag(p.M + k * 256 + q*4 + 0, a0); st_ag(p.M + k * 256 + q*4 + 1, a1);
                st_ag(p.M + k * 256 + q*4 + 2, a2); st_ag(p.M + k * 256 + q*4 + 3, a3);
            }
        }
        if (wvi == 0) {                           // c2 = b1 @ W2 slab
            float a0 = 0, a1 = 0, a2 = 0, a3 = 0;
            #pragma unroll
            for (int it = 0; it < 4; ++it) {
                int j = it * 64 + lane;
                float a = p.b1[j];
                a0 += a * lds[j*4+0]; a1 += a * lds[j*4+1];
                a2 += a * lds[j*4+2]; a3 += a * lds[j*4+3];
            }
            #pragma unroll
            for (int off = 32; off > 0; off >>= 1) {
                a0 += __shfl_down(a0, off, 64); a1 += __shfl_down(a1, off, 64);
                a2 += __shfl_down(a2, off, 64); a3 += __shfl_down(a3, off, 64);
            }
            if (lane == 0) {
                st_ag(p.c2 + q*4+0, a0); st_ag(p.c2 + q*4+1, a1);
                st_ag(p.c2 + q*4+2, a2); st_ag(p.c2 + q*4+3, a3);
            }
        }
    };

    // ---- tailA: fold wv for tile b, contract against x ---------------------
    auto tailA = [&]() {
        const int k = tid & 127, rg = tid >> 7;
        const int i0 = b * 128, i = i0 + k;
        const bool act = i < N;
        const int g = b / 40;
        const int jj = i - g * RB;
        float sv = 0.f;
        if (act) {
            const float* pp = p.part + (size_t)(g * 64 + rg * 8) * RB + jj;
            #pragma unroll
            for (int r = 0; r < 8; ++r) sv += ld_ag(pp + (size_t)r * RB);
        }
        lds[tid] = sv;
        __syncthreads();
        if (rg == 0) {
            float q = 0.f;
            #pragma unroll
            for (int t2 = 0; t2 < 8; ++t2) q += lds[t2 * 128 + k];
            float d = act ? p.dinv[i] : 0.f;
            lds[1024 + k] = act ? d * (q + d * p.u[i]) : 0.f;   // wv tile
        }
        __syncthreads();
        float acc = 0.f;
        #pragma unroll
        for (int m4 = 0; m4 < 16; ++m4) {
            int m = rg + 8 * m4;
            int i2 = i0 + m;
            float xv = p.x[(size_t)(i2 < N ? i2 : i0) * D_IN + k];
            acc += lds[1024 + m] * xv;
        }
        __syncthreads();
        lds[tid] = acc;
        __syncthreads();
        if (rg == 0) {
            float t2s = 0.f;
            #pragma unroll
            for (int t2 = 0; t2 < 8; ++t2) t2s += lds[t2 * 128 + k];
            st_ag(p.s_part + b * 128 + k, t2s);
        }
    };

    // ---- head (block 0 only): s/S_u fold, g, z, softmax --------------------
    auto head = [&]() {
        float* sh = lds;                          // [0..1023]
        float* ss = lds + 1024;                   // [1024..1151]
        float* gg = lds + 1152;                   // [1152..1407]
        float* zz = lds + 1408;                   // [1408..1535]
        float* red = lds + 1536;                  // [1536..1575]
        const int k = tid & 127, rg = tid >> 7;

        float a = 0.f;
        for (int q = rg; q < NTILE; q += 8) a += ld_ag(p.s_part + q * 128 + k);
        sh[tid] = a;
        float v = (tid < NTILE) ? ld_ag(p.S_u_part + tid) : 0.f;
        #pragma unroll
        for (int off = 32; off > 0; off >>= 1) v += __shfl_down(v, off, 64);
        __syncthreads();
        if (rg == 0) {
            float t2 = 0.f;
            #pragma unroll
            for (int q = 0; q < 8; ++q) t2 += sh[q * 128 + k];
            ss[k] = t2;
        }
        if ((tid & 63) == 0) red[tid >> 6] = v;
        __syncthreads();
        if (tid == 0) {
            float t2 = 0.f;
            #pragma unroll
            for (int q = 0; q < 16; ++q) t2 += red[q];
            red[16] = t2;
        }
        __syncthreads();
        const float S_u = red[16];

        {   // g = (s@M + S_u*c2)/n + b2
            int t = tid & 255, kg = tid >> 8;
            float acc = 0.f;
            #pragma unroll
            for (int kk = 0; kk < 32; ++kk) {
                int k2 = kg * 32 + kk;
                acc += ss[k2] * ld_ag(p.M + k2 * 256 + t);
            }
            sh[tid] = acc;
            __syncthreads();
            if (kg == 0)
                gg[t] = (sh[t] + sh[256 + t] + sh[512 + t] + sh[768 + t]
                         + S_u * ld_ag(p.c2 + t)) * p.inv_n + p.b2[t];
        }
        __syncthreads();

        {   // z = relu(g@Wd1 + bd1)
            float acc = 0.f;
            #pragma unroll
            for (int kk = 0; kk < 32; ++kk) {
                int k2 = rg * 32 + kk;
                acc += gg[k2] * p.Wd1[k2 * D_DENSE + k];
            }
            sh[tid] = acc;
            __syncthreads();
            if (rg == 0) {
                float z = 0.f;
                #pragma unroll
                for (int q = 0; q < 8; ++q) z += sh[q * 128 + k];
                zz[k] = fmaxf(z + p.bd1[k], 0.f);
            }
        }
        __syncthreads();

        float p0 = 0.f, p1 = 0.f;
        if (tid < 128) {
            float zt = zz[tid];
            p0 = zt * p.Wd2[tid * 2 + 0];
            p1 = zt * p.Wd2[tid * 2 + 1];
        }
        #pragma unroll
        for (int off = 32; off > 0; off >>= 1) {
            p0 += __shfl_down(p0, off, 64);
            p1 += __shfl_down(p1, off, 64);
        }
        if ((tid & 63) == 0) { red[tid >> 6] = p0; red[20 + (tid >> 6)] = p1; }
        __syncthreads();
        if (tid == 0) {
            float l0 = red[0] + red[1] + p.bd2[0];   // waves 0-1 only
            float l1 = red[20] + red[21] + p.bd2[1];
            float m = fmaxf(l0, l1);
            float e0 = expf(l0 - m), e1 = expf(l1 - m);
            float inv = 1.0f / (e0 + e1);
            p.out[0] = e0 * inv;
            p.out[1] = e1 * inv;
        }
    };

    // ---------------- phase schedule (relaxed epoch barriers) ---------------
    scatter(p.col, p.row, 0);                     // deg by col
    ph_arrive(p.flags, 1); ph_wait(p.flags, 1);
    if (b < NTILE) fold(0);
    else if (b < NTILE + 64) precompute();        // M=W1@W2, c2=b1@W2
    ph_arrive(p.flags, 2); ph_wait(p.flags, 2);
    scatter(p.row, p.col, 1);                     // gather dinv[c]
    ph_arrive(p.flags, 3); ph_wait(p.flags, 3);
    if (b < NTILE) fold(1);                       // u, S_u partials
    ph_arrive(p.flags, 4); ph_wait(p.flags, 4);
    scatter(p.row, p.col, 2);                     // gather dinv[c]*u[c]
    ph_arrive(p.flags, 5); ph_wait(p.flags, 5);
    if (b < NTILE) tailA();                       // wv tile + x contraction
    ph_arrive(p.flags, 6);
    if (b != 0) return;
    ph_wait(p.flags, 6);
    head();
}

extern "C" void kernel_launch(void* const* d_in, const int* in_sizes, int n_in,
                              void* d_out, int out_size, void* d_ws, size_t ws_size,
                              hipStream_t stream) {
    const int N = in_sizes[0] / D_IN;      // 20000
    const int E = in_sizes[1] / 2;         // 640000
    const int* ei = (const int*)d_in[1];

    Params p;
    p.x   = (const float*)d_in[0];
    p.row = ei;
    p.col = ei + E;
    p.w   = (const float*)d_in[2];
    p.W1  = (const float*)d_in[3];
    p.b1  = (const float*)d_in[4];
    p.W2  = (const float*)d_in[5];
    p.b2  = (const float*)d_in[6];
    p.Wd1 = (const float*)d_in[7];
    p.bd1 = (const float*)d_in[8];
    p.Wd2 = (const float*)d_in[9];
    p.bd2 = (const float*)d_in[10];
    p.out = (float*)d_out;

    // workspace (floats); all offsets 128B-aligned; flags self-init via poison
    float* fws   = (float*)d_ws;
    p.flags      = (int*)fws;                              // 256
    p.part       = fws + 256;                              // 256*RB = 1.31M
    p.dinv       = p.part + (size_t)256 * RB;              // N (80000 B, 128|)
    p.u          = p.dinv + N;                             // N
    p.s_part     = p.u + N;                                // NTILE*128
    p.S_u_part   = p.s_part + (size_t)NTILE * D_IN;        // 160 (padded)
    p.M          = p.S_u_part + 160;                       // 128*256
    p.c2         = p.M + D_IN * D_HID;                     // 256
    p.N = N; p.E = E; p.inv_n = 1.0f / (float)N;

    k_all<<<256, 1024, 0, stream>>>(p);
}

// Round 13
// 150.356 us; speedup vs baseline: 1.0844x; 1.0844x over previous
//
#include <hip/hip_runtime.h>
#include <hip/hip_bf16.h>

// GCN forward, algebraically collapsed (no nonlinearity between convs, mean pool):
//   g = (1/n)*((A^T u)^T X)@W1@W2 + (1/n)*(sum u)*(b1@W2) + b2,  A = D^-1/2(Adj+I)D^-1/2
// Round 13: fused kernel, relaxed(sc1) cross-phase buffers + epoch-flag
// barriers (~4us each, round 11). Fixes round-12 regression: gathers are
// PREDICATED by the range check again (round 12 hoisted them -> 4x gather
// issue count), and (dinv,u) packed as float2 so the mode-2 gather is ONE
// 8B agent-load. Keeps: 4 ranges x 64 slices (5 MB partials, 8-load folds),
// XCD-aligned slice mapping, int4 edge loads.

#define D_IN 128
#define D_HID 256
#define D_DENSE 128
#define RB 5120           // bins per range (20 KB LDS); range 3 holds 4640
#define PER 10000         // edges per slice (64 slices x 10000 = E)
#define NTILE 157         // ceil(20000/128) fold/tail tiles (128 | 5120)

__device__ __forceinline__ float ld_ag(const float* p) {
    return __hip_atomic_load(p, __ATOMIC_RELAXED, __HIP_MEMORY_SCOPE_AGENT);
}
__device__ __forceinline__ void st_ag(float* p, float v) {
    __hip_atomic_store(p, v, __ATOMIC_RELAXED, __HIP_MEMORY_SCOPE_AGENT);
}
__device__ __forceinline__ float2 ld_ag2(const float2* p) {
    union { unsigned long long u; float2 f; } x;
    x.u = __hip_atomic_load((const unsigned long long*)p,
                            __ATOMIC_RELAXED, __HIP_MEMORY_SCOPE_AGENT);
    return x.f;
}
// epoch-flag barrier: no init needed (0xAA poison as int is negative < phase)
__device__ __forceinline__ void ph_arrive(int* flags, int phase) {
    __syncthreads();   // drains vmcnt before s_barrier -> stores visible
    if (threadIdx.x == 0)
        __hip_atomic_store(&flags[blockIdx.x], phase,
                           __ATOMIC_RELAXED, __HIP_MEMORY_SCOPE_AGENT);
}
__device__ __forceinline__ void ph_wait(int* flags, int phase) {
    if (threadIdx.x < 256) {
        while (__hip_atomic_load(&flags[threadIdx.x],
                                 __ATOMIC_RELAXED, __HIP_MEMORY_SCOPE_AGENT) < phase)
            __builtin_amdgcn_s_sleep(2);
    }
    __syncthreads();
}

struct Params {
    const float* x; const int* row; const int* col; const float* w;
    const float* W1; const float* b1; const float* W2; const float* b2;
    const float* Wd1; const float* bd1; const float* Wd2; const float* bd2;
    float* out;
    float* part; float2* du; float* s_part; float* S_u_part;
    float* M; float* c2; int* flags;
    int N; int E; float inv_n;
};

__global__ __launch_bounds__(1024) void k_all(Params p) {
    __shared__ float lds[RB];                     // 20 KB, reused per phase
    const int b = blockIdx.x, tid = threadIdx.x;
    const int N = p.N, E = p.E;
    const float* duf = (const float*)p.du;        // scalar view (2 floats/node)

    // ---- edge scatter: block (range g, slice s); predicated gathers --------
    auto scatter = [&](const int* tgt, const int* src, int mode) {
        const int g = b >> 6, s = b & 63;         // b%8 == s%8: 4 range-blocks/XCD
        const int base = g * RB;
        const int lim  = min(RB, N - base);
        const int e0 = s * PER, e1 = min(e0 + PER, E);
        float* outp = p.part + (size_t)b * RB;    // replica (g,s)
        for (int i = tid; i < lim; i += 1024) lds[i] = 0.f;
        __syncthreads();
        for (int e = e0 + tid * 4; e + 3 < e1; e += 4096) {
            int4   t4 = *(const int4*)(tgt + e);
            float4 w4 = *(const float4*)(p.w + e);
            int4   s4 = (mode != 0) ? *(const int4*)(src + e) : int4{0,0,0,0};
            int t0 = t4.x - base, t1 = t4.y - base;
            int t2 = t4.z - base, t3 = t4.w - base;
            // gathers PREDICATED on range membership (~25% of lanes execute)
            if ((unsigned)t0 < (unsigned)lim) {
                float v = w4.x;
                if (mode == 1) v *= ld_ag(duf + 2 * s4.x);
                else if (mode == 2) { float2 f = ld_ag2(p.du + s4.x); v *= f.x * f.y; }
                atomicAdd(&lds[t0], v);
            }
            if ((unsigned)t1 < (unsigned)lim) {
                float v = w4.y;
                if (mode == 1) v *= ld_ag(duf + 2 * s4.y);
                else if (mode == 2) { float2 f = ld_ag2(p.du + s4.y); v *= f.x * f.y; }
                atomicAdd(&lds[t1], v);
            }
            if ((unsigned)t2 < (unsigned)lim) {
                float v = w4.z;
                if (mode == 1) v *= ld_ag(duf + 2 * s4.z);
                else if (mode == 2) { float2 f = ld_ag2(p.du + s4.z); v *= f.x * f.y; }
                atomicAdd(&lds[t2], v);
            }
            if ((unsigned)t3 < (unsigned)lim) {
                float v = w4.w;
                if (mode == 1) v *= ld_ag(duf + 2 * s4.w);
                else if (mode == 2) { float2 f = ld_ag2(p.du + s4.w); v *= f.x * f.y; }
                atomicAdd(&lds[t3], v);
            }
        }
        __syncthreads();
        for (int i = tid; i < lim; i += 1024) st_ag(outp + i, lds[i]);
    };

    // ---- fold 64 replicas + node math (blocks 0..NTILE-1) ------------------
    auto fold = [&](int mode) {
        const int j = tid & 127, rg = tid >> 7;   // rg in [0,8): 8 replicas each
        const int i = b * 128 + j;
        const bool act = i < N;
        const int g = b / 40;                     // tile-uniform (128 | 5120)
        const int jj = i - g * RB;
        float sv = 0.f;
        if (act) {
            const float* pp = p.part + (size_t)(g * 64 + rg * 8) * RB + jj;
            #pragma unroll
            for (int r = 0; r < 8; ++r) sv += ld_ag(pp + (size_t)r * RB);
        }
        lds[rg * 128 + j] = sv;
        __syncthreads();
        float ui = 0.f;
        if (rg == 0) {
            float tot = 0.f;
            #pragma unroll
            for (int q = 0; q < 8; ++q) tot += lds[q * 128 + j];
            if (act) {
                if (mode == 0) {
                    st_ag((float*)(p.du + i), rsqrtf(tot + 1.0f));    // du[i].x
                } else {
                    float d = ld_ag((const float*)(p.du + i));        // du[i].x
                    ui = d * (tot + d);
                    st_ag((float*)(p.du + i) + 1, ui);                // du[i].y
                }
            }
        }
        if (mode == 1) {                          // per-block S_u partial
            float v = ui;                         // nonzero only waves 0-1
            #pragma unroll
            for (int off = 32; off > 0; off >>= 1) v += __shfl_down(v, off, 64);
            if (tid < 128 && (tid & 63) == 0) lds[1028 + (tid >> 6)] = v;
            __syncthreads();
            if (tid == 0) st_ag(p.S_u_part + b, lds[1028] + lds[1029]);
        }
    };

    // ---- M = W1@W2, c2 = b1@W2 (blocks NTILE..NTILE+63 during F0) ----------
    auto precompute = [&]() {
        int q = b - NTILE;                        // 0..63: 4 cols of M each
        lds[tid] = p.W2[(tid >> 2) * 256 + q * 4 + (tid & 3)];
        __syncthreads();
        int wvi = tid >> 6, lane = tid & 63;
        for (int kr = 0; kr < 8; ++kr) {
            int k = wvi * 8 + kr;                 // 16 waves x 8 = 128 rows
            float a0 = 0, a1 = 0, a2 = 0, a3 = 0;
            #pragma unroll
            for (int it = 0; it < 4; ++it) {
                int j = it * 64 + lane;
                float a = p.W1[k * 256 + j];
                a0 += a * lds[j*4+0]; a1 += a * lds[j*4+1];
                a2 += a * lds[j*4+2]; a3 += a * lds[j*4+3];
            }
            #pragma unroll
            for (int off = 32; off > 0; off >>= 1) {
                a0 += __shfl_down(a0, off, 64); a1 += __shfl_down(a1, off, 64);
                a2 += __shfl_down(a2, off, 64); a3 += __shfl_down(a3, off, 64);
            }
            if (lane == 0) {
                st_ag(p.M + k * 256 + q*4 + 0, a0); st_ag(p.M + k * 256 + q*4 + 1, a1);
                st_ag(p.M + k * 256 + q*4 + 2, a2); st_ag(p.M + k * 256 + q*4 + 3, a3);
            }
        }
        if (wvi == 0) {                           // c2 = b1 @ W2 slab
            float a0 = 0, a1 = 0, a2 = 0, a3 = 0;
            #pragma unroll
            for (int it = 0; it < 4; ++it) {
                int j = it * 64 + lane;
                float a = p.b1[j];
                a0 += a * lds[j*4+0]; a1 += a * lds[j*4+1];
                a2 += a * lds[j*4+2]; a3 += a * lds[j*4+3];
            }
            #pragma unroll
            for (int off = 32; off > 0; off >>= 1) {
                a0 += __shfl_down(a0, off, 64); a1 += __shfl_down(a1, off, 64);
                a2 += __shfl_down(a2, off, 64); a3 += __shfl_down(a3, off, 64);
            }
            if (lane == 0) {
                st_ag(p.c2 + q*4+0, a0); st_ag(p.c2 + q*4+1, a1);
                st_ag(p.c2 + q*4+2, a2); st_ag(p.c2 + q*4+3, a3);
            }
        }
    };

    // ---- tailA: fold wv for tile b, contract against x ---------------------
    auto tailA = [&]() {
        const int k = tid & 127, rg = tid >> 7;
        const int i0 = b * 128, i = i0 + k;
        const bool act = i < N;
        const int g = b / 40;
        const int jj = i - g * RB;
        float sv = 0.f;
        if (act) {
            const float* pp = p.part + (size_t)(g * 64 + rg * 8) * RB + jj;
            #pragma unroll
            for (int r = 0; r < 8; ++r) sv += ld_ag(pp + (size_t)r * RB);
        }
        lds[tid] = sv;
        __syncthreads();
        if (rg == 0) {
            float q = 0.f;
            #pragma unroll
            for (int t2 = 0; t2 < 8; ++t2) q += lds[t2 * 128 + k];
            float2 f = act ? ld_ag2(p.du + i) : float2{0.f, 0.f};
            lds[1024 + k] = act ? f.x * (q + f.x * f.y) : 0.f;   // wv tile
        }
        __syncthreads();
        float acc = 0.f;
        #pragma unroll
        for (int m4 = 0; m4 < 16; ++m4) {
            int m = rg + 8 * m4;
            int i2 = i0 + m;
            float xv = p.x[(size_t)(i2 < N ? i2 : i0) * D_IN + k];
            acc += lds[1024 + m] * xv;
        }
        __syncthreads();
        lds[tid] = acc;
        __syncthreads();
        if (rg == 0) {
            float t2s = 0.f;
            #pragma unroll
            for (int t2 = 0; t2 < 8; ++t2) t2s += lds[t2 * 128 + k];
            st_ag(p.s_part + b * 128 + k, t2s);
        }
    };

    // ---- head (block 0 only): s/S_u fold, g, z, softmax --------------------
    auto head = [&]() {
        float* sh = lds;                          // [0..1023]
        float* ss = lds + 1024;                   // [1024..1151]
        float* gg = lds + 1152;                   // [1152..1407]
        float* zz = lds + 1408;                   // [1408..1535]
        float* red = lds + 1536;                  // [1536..1575]
        const int k = tid & 127, rg = tid >> 7;

        float a = 0.f;
        for (int q = rg; q < NTILE; q += 8) a += ld_ag(p.s_part + q * 128 + k);
        sh[tid] = a;
        float v = (tid < NTILE) ? ld_ag(p.S_u_part + tid) : 0.f;
        #pragma unroll
        for (int off = 32; off > 0; off >>= 1) v += __shfl_down(v, off, 64);
        __syncthreads();
        if (rg == 0) {
            float t2 = 0.f;
            #pragma unroll
            for (int q = 0; q < 8; ++q) t2 += sh[q * 128 + k];
            ss[k] = t2;
        }
        if ((tid & 63) == 0) red[tid >> 6] = v;
        __syncthreads();
        if (tid == 0) {
            float t2 = 0.f;
            #pragma unroll
            for (int q = 0; q < 16; ++q) t2 += red[q];
            red[16] = t2;
        }
        __syncthreads();
        const float S_u = red[16];

        {   // g = (s@M + S_u*c2)/n + b2
            int t = tid & 255, kg = tid >> 8;
            float acc = 0.f;
            #pragma unroll
            for (int kk = 0; kk < 32; ++kk) {
                int k2 = kg * 32 + kk;
                acc += ss[k2] * ld_ag(p.M + k2 * 256 + t);
            }
            sh[tid] = acc;
            __syncthreads();
            if (kg == 0)
                gg[t] = (sh[t] + sh[256 + t] + sh[512 + t] + sh[768 + t]
                         + S_u * ld_ag(p.c2 + t)) * p.inv_n + p.b2[t];
        }
        __syncthreads();

        {   // z = relu(g@Wd1 + bd1)
            float acc = 0.f;
            #pragma unroll
            for (int kk = 0; kk < 32; ++kk) {
                int k2 = rg * 32 + kk;
                acc += gg[k2] * p.Wd1[k2 * D_DENSE + k];
            }
            sh[tid] = acc;
            __syncthreads();
            if (rg == 0) {
                float z = 0.f;
                #pragma unroll
                for (int q = 0; q < 8; ++q) z += sh[q * 128 + k];
                zz[k] = fmaxf(z + p.bd1[k], 0.f);
            }
        }
        __syncthreads();

        float p0 = 0.f, p1 = 0.f;
        if (tid < 128) {
            float zt = zz[tid];
            p0 = zt * p.Wd2[tid * 2 + 0];
            p1 = zt * p.Wd2[tid * 2 + 1];
        }
        #pragma unroll
        for (int off = 32; off > 0; off >>= 1) {
            p0 += __shfl_down(p0, off, 64);
            p1 += __shfl_down(p1, off, 64);
        }
        if ((tid & 63) == 0) { red[tid >> 6] = p0; red[20 + (tid >> 6)] = p1; }
        __syncthreads();
        if (tid == 0) {
            float l0 = red[0] + red[1] + p.bd2[0];   // waves 0-1 only
            float l1 = red[20] + red[21] + p.bd2[1];
            float m = fmaxf(l0, l1);
            float e0 = expf(l0 - m), e1 = expf(l1 - m);
            float inv = 1.0f / (e0 + e1);
            p.out[0] = e0 * inv;
            p.out[1] = e1 * inv;
        }
    };

    // ---------------- phase schedule (relaxed epoch barriers) ---------------
    scatter(p.col, p.row, 0);                     // deg by col
    ph_arrive(p.flags, 1); ph_wait(p.flags, 1);
    if (b < NTILE) fold(0);
    else if (b < NTILE + 64) precompute();        // M=W1@W2, c2=b1@W2
    ph_arrive(p.flags, 2); ph_wait(p.flags, 2);
    scatter(p.row, p.col, 1);                     // gather dinv[c]
    ph_arrive(p.flags, 3); ph_wait(p.flags, 3);
    if (b < NTILE) fold(1);                       // u, S_u partials
    ph_arrive(p.flags, 4); ph_wait(p.flags, 4);
    scatter(p.row, p.col, 2);                     // gather dinv[c]*u[c]
    ph_arrive(p.flags, 5); ph_wait(p.flags, 5);
    if (b < NTILE) tailA();                       // wv tile + x contraction
    ph_arrive(p.flags, 6);
    if (b != 0) return;
    ph_wait(p.flags, 6);
    head();
}

extern "C" void kernel_launch(void* const* d_in, const int* in_sizes, int n_in,
                              void* d_out, int out_size, void* d_ws, size_t ws_size,
                              hipStream_t stream) {
    const int N = in_sizes[0] / D_IN;      // 20000
    const int E = in_sizes[1] / 2;         // 640000
    const int* ei = (const int*)d_in[1];

    Params p;
    p.x   = (const float*)d_in[0];
    p.row = ei;
    p.col = ei + E;
    p.w   = (const float*)d_in[2];
    p.W1  = (const float*)d_in[3];
    p.b1  = (const float*)d_in[4];
    p.W2  = (const float*)d_in[5];
    p.b2  = (const float*)d_in[6];
    p.Wd1 = (const float*)d_in[7];
    p.bd1 = (const float*)d_in[8];
    p.Wd2 = (const float*)d_in[9];
    p.bd2 = (const float*)d_in[10];
    p.out = (float*)d_out;

    // workspace (floats); all offsets 8B-aligned; flags self-init via poison
    float* fws   = (float*)d_ws;
    p.flags      = (int*)fws;                              // 256
    p.part       = fws + 256;                              // 256*RB = 1.31M
    p.du         = (float2*)(p.part + (size_t)256 * RB);   // N float2 (8B-aligned)
    p.s_part     = (float*)(p.du + N);                     // NTILE*128
    p.S_u_part   = p.s_part + (size_t)NTILE * D_IN;        // 160 (padded)
    p.M          = p.S_u_part + 160;                       // 128*256
    p.c2         = p.M + D_IN * D_HID;                     // 256
    p.N = N; p.E = E; p.inv_n = 1.0f / (float)N;

    k_all<<<256, 1024, 0, stream>>>(p);
}